// Round 14
// baseline (176.466 us; speedup 1.0000x reference)
//
#include <hip/hip_runtime.h>

typedef __attribute__((ext_vector_type(8))) short bf16x8;
typedef __attribute__((ext_vector_type(4))) unsigned short u16x4;
typedef __attribute__((ext_vector_type(4))) float f32x4;

#define TM 8           // tokens per block
#define FPAD 272       // feat row stride (u16): 544 B = 34*16B -> uniform-4 bank tiling

__device__ __forceinline__ unsigned short f2bf(float f) {
    unsigned u = __builtin_bit_cast(unsigned, f);
    u += 0x7FFFu + ((u >> 16) & 1u);        // RNE
    return (unsigned short)(u >> 16);
}
__device__ __forceinline__ float bf2f(unsigned short h) {
    return __builtin_bit_cast(float, (unsigned)h << 16);
}

// ws layout: fragment order, 5 matrices. u16 index = (((tile*8+ks)*5 + w)*64 + lane)*8 + j
// lane = aq*16 + col ; value = Wmat_w[o = tile*16+col][c = ks*32 + aq*8 + j]
// w: 0 WTT, 1 WTD, 2 WVD, 3 WA, 4 WV.  Total 327680 u16 = 655 KB.
__device__ __forceinline__ int widx(int w, int o, int c) {
    int tile = o >> 4, col = o & 15;
    int ks = c >> 5, aq = (c >> 3) & 3, j = c & 7;
    return (((tile * 8 + ks) * 5 + w) * 64 + aq * 16 + col) * 8 + j;
}

// ---------------- prep: Wa = Wtr(I+Wtt), Wv = Wdv(I-Wtt), bf16 + fragment order ----------------
__global__ __launch_bounds__(512)
void avd_prep_kernel(const float* __restrict__ Wtt, const float* __restrict__ Wtr,
                     const float* __restrict__ Wtd, const float* __restrict__ Wvd,
                     const float* __restrict__ Wdv, unsigned short* __restrict__ ws)
{
    __shared__ float ra[2][256], rv[2][256];
    const int half = threadIdx.x >> 8;          // 0..1
    const int c    = threadIdx.x & 255;
    const int o    = blockIdx.x * 2 + half;
    ra[half][c] = Wtr[o * 256 + c];
    rv[half][c] = Wdv[o * 256 + c];
    __syncthreads();
    float sa = 0.f, sv = 0.f;
    #pragma unroll 8
    for (int k = 0; k < 256; ++k) {
        float w = Wtt[k * 256 + c];             // coalesced across c
        sa += ra[half][k] * w;
        sv += rv[half][k] * w;
    }
    const int idx = o * 256 + c;
    ws[widx(0, o, c)] = f2bf(Wtt[idx]);
    ws[widx(1, o, c)] = f2bf(Wtd[idx]);
    ws[widx(2, o, c)] = f2bf(Wvd[idx]);
    ws[widx(3, o, c)] = f2bf(Wtr[idx] + sa);    // Wa = Wtr(I+Wtt)
    ws[widx(4, o, c)] = f2bf(Wdv[idx] - sv);    // Wv = Wdv(I-Wtt)
}

// ---------------- main: r12 structure, reg-budget widened to 3 waves/SIMD ----------------
__global__ __launch_bounds__(512, 3)
void avd_main_kernel(const float* __restrict__ xa, const float* __restrict__ xv,
                     const float* __restrict__ xd,
                     const unsigned short* __restrict__ ws,
                     float* __restrict__ out)
{
    // feat row = m*13 + p ; p 0..8: x_d (q=i*3+j), 9: x_a, 10..12: x_v comps.
    __shared__ __attribute__((aligned(16))) unsigned short feat[104][FPAD];    // 55.25 KB

    const int tid  = threadIdx.x;
    const int lane = tid & 63;
    const int wid  = tid >> 6;          // 0..7
    const int m0   = blockIdx.x * TM;

    float* out_xa = out;                 // 16384*256
    float* out_xv = out + 4194304;       // + 16384*256*3
    float* out_xd = out + 16777216;      // + 16384*256*9

    // ---- stage: wave `wid` owns token m = wid; dense f32x4 NT loads, u16 LDS scatter ----
    {
        const int m  = wid;
        const int mx = m << 3;
        const f32x4* srcd = (const f32x4*)(xd + (size_t)(m0 + m) * 2304);
        #pragma unroll
        for (int it = 0; it < 9; ++it) {
            int ch = lane + it * 64;
            f32x4 v = __builtin_nontemporal_load(&srcd[ch]);
            int e0 = ch * 4;
            #pragma unroll
            for (int j = 0; j < 4; ++j) {
                int e = e0 + j;
                int c = e / 9;
                int q = e - c * 9;
                feat[m * 13 + q][c ^ mx] = f2bf(v[j]);
            }
        }
        const f32x4* srcv = (const f32x4*)(xv + (size_t)(m0 + m) * 768);
        #pragma unroll
        for (int it = 0; it < 3; ++it) {
            int ch = lane + it * 64;
            f32x4 v = __builtin_nontemporal_load(&srcv[ch]);
            int e0 = ch * 4;
            #pragma unroll
            for (int j = 0; j < 4; ++j) {
                int e = e0 + j;
                int c = e / 3;
                int i = e - c * 3;
                feat[m * 13 + 10 + i][c ^ mx] = f2bf(v[j]);
            }
        }
        {
            f32x4 v = __builtin_nontemporal_load(&((const f32x4*)(xa + (size_t)(m0 + m) * 256))[lane]);
            u16x4 w4;
            #pragma unroll
            for (int j = 0; j < 4; ++j) w4[j] = f2bf(v[j]);
            *(u16x4*)&feat[m * 13 + 9][(lane * 4) ^ mx] = w4;
        }
    }
    __syncthreads();    // the only barrier: feat is read-only from here on

    const int am  = lane & 7;    // token row m (A rows 8..15 hold the paired slot)
    const int aq  = lane >> 4;   // k-quarter
    const int col = lane & 15;   // output channel within tile

    #pragma unroll 1
    for (int t = 0; t < 2; ++t) {
        const int o = t * 128 + wid * 16 + col;

        // paired accs: {low-slot | high-slot} ; singles duplicate rows
        f32x4 cP0{}, cP1{}, cP2{}, cP3{};   // (t0|t1)(t2|t3)(t4|t5)(t6|t7)
        f32x4 cS8{}, cSd{};                 // t8 ; delta (xa x Wtd)      [dup rows]
        f32x4 cW01{}, cW2{};                // (w0|w1) ; w2 [dup rows]
        f32x4 cA04{}, cA8{};                // (Wa@d0|Wa@d4) ; Wa@d8 [dup rows]
        f32x4 cV57{}, cV62{}, cV13{};       // (Wv@d5|Wv@d7)(Wv@d6|Wv@d2)(Wv@d1|Wv@d3)

#define AP(qa, qb) (*(const bf16x8*)(fb + ((lane & 8) ? (qb) : (qa)) * FPAD))
#define AD(q)      (*(const bf16x8*)(fb + (q) * FPAD))

        #pragma unroll 2
        for (int ks = 0; ks < 8; ++ks) {
            const int csw = (ks * 32 + aq * 8) ^ (am << 3);
            const unsigned short* fb = &feat[am * 13][csw];
            bf16x8 a01 = AP(0, 1),  a23 = AP(2, 3), a45 = AP(4, 5), a67 = AP(6, 7);
            bf16x8 a8  = AD(8),     a9  = AD(9);
            bf16x8 aW  = AP(10, 11), aW2 = AD(12);
            bf16x8 a04 = AP(0, 4),  a57 = AP(5, 7), a62 = AP(6, 2), a13 = AP(1, 3);

            // dense fragment-ordered weight loads: 16 B/lane contiguous per matrix
            const unsigned short* wsb = ws + ((((t * 8 + wid) * 8 + ks) * 5) * 64 + lane) * 8;
            bf16x8 b_tt = *(const bf16x8*)(wsb + 0 * 512);
            bf16x8 b_td = *(const bf16x8*)(wsb + 1 * 512);
            bf16x8 b_vd = *(const bf16x8*)(wsb + 2 * 512);
            bf16x8 b_wa = *(const bf16x8*)(wsb + 3 * 512);
            bf16x8 b_wv = *(const bf16x8*)(wsb + 4 * 512);

            cP0  = __builtin_amdgcn_mfma_f32_16x16x32_bf16(a01, b_tt, cP0, 0, 0, 0);
            cP1  = __builtin_amdgcn_mfma_f32_16x16x32_bf16(a23, b_tt, cP1, 0, 0, 0);
            cP2  = __builtin_amdgcn_mfma_f32_16x16x32_bf16(a45, b_tt, cP2, 0, 0, 0);
            cP3  = __builtin_amdgcn_mfma_f32_16x16x32_bf16(a67, b_tt, cP3, 0, 0, 0);
            cS8  = __builtin_amdgcn_mfma_f32_16x16x32_bf16(a8,  b_tt, cS8, 0, 0, 0);
            cSd  = __builtin_amdgcn_mfma_f32_16x16x32_bf16(a9,  b_td, cSd, 0, 0, 0);
            cW01 = __builtin_amdgcn_mfma_f32_16x16x32_bf16(aW,  b_vd, cW01, 0, 0, 0);
            cW2  = __builtin_amdgcn_mfma_f32_16x16x32_bf16(aW2, b_vd, cW2, 0, 0, 0);
            cA04 = __builtin_amdgcn_mfma_f32_16x16x32_bf16(a04, b_wa, cA04, 0, 0, 0);
            cA8  = __builtin_amdgcn_mfma_f32_16x16x32_bf16(a8,  b_wa, cA8, 0, 0, 0);
            cV57 = __builtin_amdgcn_mfma_f32_16x16x32_bf16(a57, b_wv, cV57, 0, 0, 0);
            cV62 = __builtin_amdgcn_mfma_f32_16x16x32_bf16(a62, b_wv, cV62, 0, 0, 0);
            cV13 = __builtin_amdgcn_mfma_f32_16x16x32_bf16(a13, b_wv, cV13, 0, 0, 0);
        }

        // ---- identity K-step: fold xd/xa residuals into accs (t[q] += d[T(q)]) ----
        // B = one-hot: bi[n][k] = 1 iff k_global == o(n). Dup accs use AD (both halves).
        {
            const int ob   = t * 128 + wid * 16;
            const int cw32 = ob & ~31;           // 32-aligned c-window containing o-range
            const int hit  = (ob & 31) + col - aq * 8;
            bf16x8 bi;
            #pragma unroll
            for (int j = 0; j < 8; ++j) bi[j] = (short)((hit == j) ? 0x3F80 : 0);
            const int csw = (cw32 + aq * 8) ^ (am << 3);
            const unsigned short* fb = &feat[am * 13][csw];
            // T: 0->0 1->3 2->6 3->1 4->4 5->7 6->2 7->5 8->8
            cP0 = __builtin_amdgcn_mfma_f32_16x16x32_bf16(AP(0, 3), bi, cP0, 0, 0, 0);
            cP1 = __builtin_amdgcn_mfma_f32_16x16x32_bf16(AP(6, 1), bi, cP1, 0, 0, 0);
            cP2 = __builtin_amdgcn_mfma_f32_16x16x32_bf16(AP(4, 7), bi, cP2, 0, 0, 0);
            cP3 = __builtin_amdgcn_mfma_f32_16x16x32_bf16(AP(2, 5), bi, cP3, 0, 0, 0);
            cS8 = __builtin_amdgcn_mfma_f32_16x16x32_bf16(AD(8),    bi, cS8, 0, 0, 0);
            cA8 = __builtin_amdgcn_mfma_f32_16x16x32_bf16(AD(9),    bi, cA8, 0, 0, 0);
        }
#undef AP
#undef AD

        // half-exchange: e = low-slot value on every lane, oo = high-slot value.
#define SWAPEO(e, oo, src) { \
            _Pragma("unroll") \
            for (int j = 0; j < 4; ++j) { \
                float a_ = (src)[j], b_ = (src)[j]; \
                asm volatile("v_permlane32_swap_b32 %0, %1" : "+v"(a_), "+v"(b_)); \
                (e)[j] = a_; (oo)[j] = b_; } }
        f32x4 t0v, t1v, t2v, t3v, t4v, t5v, t6v, t7v;
        f32x4 w0v, w1v, xa0v, xa4v, a5v, a7v, a6v, a2v, a1v, a3v;
        SWAPEO(t0v, t1v, cP0);  SWAPEO(t2v, t3v, cP1);
        SWAPEO(t4v, t5v, cP2);  SWAPEO(t6v, t7v, cP3);
        SWAPEO(w0v, w1v, cW01); SWAPEO(xa0v, xa4v, cA04);
        SWAPEO(a5v, a7v, cV57); SWAPEO(a6v, a2v, cV62); SWAPEO(a1v, a3v, cV13);
#undef SWAPEO

        // epilogue: residual-free xd/xa (identity-folded); xv residual from LDS.
        // Direct cached scattered stores. lane<32 -> r=0,1 ; lane>=32 -> r=2,3
        {
            const int hi = (lane >> 4) & 1;
#define EPI(R)                                                                  \
            {                                                                   \
                const int m   = hi * 4 + (R);                                   \
                const int cso = o ^ (m << 3);                                   \
                const float delta = cSd[(R)];                                   \
                const float w0 = w0v[(R)], w1 = w1v[(R)], w2 = cW2[(R)];        \
                const size_t row = (size_t)(m0 + m) * 256 + o;                  \
                float* po = out_xd + row * 9;                                   \
                po[0] = t0v[(R)] + delta;                                       \
                po[1] = t3v[(R)] - w2;                                          \
                po[2] = t6v[(R)] + w1;                                          \
                po[3] = t1v[(R)] + w2;                                          \
                po[4] = t4v[(R)] + delta;                                       \
                po[5] = t7v[(R)] - w0;                                          \
                po[6] = t2v[(R)] - w1;                                          \
                po[7] = t5v[(R)] + w0;                                          \
                po[8] = cS8[(R)] + delta;                                       \
                out_xa[row] = xa0v[(R)] + xa4v[(R)] + cA8[(R)];                 \
                const size_t vrow = row * 3;                                    \
                out_xv[vrow + 0] = bf2f(feat[m * 13 + 10][cso]) + a5v[(R)] - a7v[(R)]; \
                out_xv[vrow + 1] = bf2f(feat[m * 13 + 11][cso]) + a6v[(R)] - a2v[(R)]; \
                out_xv[vrow + 2] = bf2f(feat[m * 13 + 12][cso]) + a1v[(R)] - a3v[(R)]; \
            }
            if (lane < 32) { EPI(0); EPI(1); }
            else           { EPI(2); EPI(3); }
#undef EPI
        }
        // no barrier: feat stays read-only, outputs disjoint per lane
    }
}

extern "C" void kernel_launch(void* const* d_in, const int* in_sizes, int n_in,
                              void* d_out, int out_size, void* d_ws, size_t ws_size,
                              hipStream_t stream) {
    const float* xa  = (const float*)d_in[0];
    const float* xv  = (const float*)d_in[1];
    const float* xd  = (const float*)d_in[2];
    const float* Wtt = (const float*)d_in[3];
    const float* Wtr = (const float*)d_in[4];
    const float* Wtd = (const float*)d_in[5];
    const float* Wvd = (const float*)d_in[6];
    const float* Wdv = (const float*)d_in[7];
    unsigned short* ws = (unsigned short*)d_ws;
    float* out = (float*)d_out;

    avd_prep_kernel<<<dim3(128), dim3(512), 0, stream>>>(Wtt, Wtr, Wtd, Wvd, Wdv, ws);
    avd_main_kernel<<<dim3(16384 / TM), dim3(512), 0, stream>>>(xa, xv, xd, ws, out);
}

// Round 15
// 143.552 us; speedup vs baseline: 1.2293x; 1.2293x over previous
//
#include <hip/hip_runtime.h>

typedef __attribute__((ext_vector_type(8))) short bf16x8;
typedef __attribute__((ext_vector_type(4))) unsigned short u16x4;
typedef __attribute__((ext_vector_type(4))) float f32x4;

#define TM 8           // tokens per block
#define FPAD 272       // feat row stride (u16): 544 B = 34*16B -> uniform-4 bank tiling

__device__ __forceinline__ unsigned short f2bf(float f) {
    unsigned u = __builtin_bit_cast(unsigned, f);
    u += 0x7FFFu + ((u >> 16) & 1u);        // RNE
    return (unsigned short)(u >> 16);
}
__device__ __forceinline__ float bf2f(unsigned short h) {
    return __builtin_bit_cast(float, (unsigned)h << 16);
}

// ws layout: fragment order, 5 matrices. u16 index = (((tile*8+ks)*5 + w)*64 + lane)*8 + j
// lane = aq*16 + col ; value = Wmat_w[o = tile*16+col][c = ks*32 + aq*8 + j]
// w: 0 WTT, 1 WTD, 2 WVD, 3 WA, 4 WV.  Total 327680 u16 = 655 KB.
__device__ __forceinline__ int widx(int w, int o, int c) {
    int tile = o >> 4, col = o & 15;
    int ks = c >> 5, aq = (c >> 3) & 3, j = c & 7;
    return (((tile * 8 + ks) * 5 + w) * 64 + aq * 16 + col) * 8 + j;
}

// ---------------- prep: Wa = Wtr(I+Wtt), Wv = Wdv(I-Wtt), bf16 + fragment order ----------------
__global__ __launch_bounds__(512)
void avd_prep_kernel(const float* __restrict__ Wtt, const float* __restrict__ Wtr,
                     const float* __restrict__ Wtd, const float* __restrict__ Wvd,
                     const float* __restrict__ Wdv, unsigned short* __restrict__ ws)
{
    __shared__ float ra[2][256], rv[2][256];
    const int half = threadIdx.x >> 8;          // 0..1
    const int c    = threadIdx.x & 255;
    const int o    = blockIdx.x * 2 + half;
    ra[half][c] = Wtr[o * 256 + c];
    rv[half][c] = Wdv[o * 256 + c];
    __syncthreads();
    float sa = 0.f, sv = 0.f;
    #pragma unroll 8
    for (int k = 0; k < 256; ++k) {
        float w = Wtt[k * 256 + c];             // coalesced across c
        sa += ra[half][k] * w;
        sv += rv[half][k] * w;
    }
    const int idx = o * 256 + c;
    ws[widx(0, o, c)] = f2bf(Wtt[idx]);
    ws[widx(1, o, c)] = f2bf(Wtd[idx]);
    ws[widx(2, o, c)] = f2bf(Wvd[idx]);
    ws[widx(3, o, c)] = f2bf(Wtr[idx] + sa);    // Wa = Wtr(I+Wtt)
    ws[widx(4, o, c)] = f2bf(Wdv[idx] - sv);    // Wv = Wdv(I-Wtt)
}

// ---------------- main: single-layer fused, slot-paired MFMAs, identity-residual ----------------
__global__ __launch_bounds__(512, 4)
void avd_main_kernel(const float* __restrict__ xa, const float* __restrict__ xv,
                     const float* __restrict__ xd,
                     const unsigned short* __restrict__ ws,
                     float* __restrict__ out)
{
    // feat row = m*13 + p ; p 0..8: x_d (q=i*3+j), 9: x_a, 10..12: x_v comps.
    __shared__ __attribute__((aligned(16))) unsigned short feat[104][FPAD];    // 55.25 KB

    const int tid  = threadIdx.x;
    const int lane = tid & 63;
    const int wid  = tid >> 6;          // 0..7
    const int m0   = blockIdx.x * TM;

    float* out_xa = out;                 // 16384*256
    float* out_xv = out + 4194304;       // + 16384*256*3
    float* out_xd = out + 16777216;      // + 16384*256*9

    // ---- stage: wave `wid` owns token m = wid; dense f32x4 NT loads, u16 LDS scatter ----
    {
        const int m  = wid;
        const int mx = m << 3;
        const f32x4* srcd = (const f32x4*)(xd + (size_t)(m0 + m) * 2304);
        #pragma unroll
        for (int it = 0; it < 9; ++it) {
            int ch = lane + it * 64;
            f32x4 v = __builtin_nontemporal_load(&srcd[ch]);
            int e0 = ch * 4;
            #pragma unroll
            for (int j = 0; j < 4; ++j) {
                int e = e0 + j;
                int c = e / 9;
                int q = e - c * 9;
                feat[m * 13 + q][c ^ mx] = f2bf(v[j]);
            }
        }
        const f32x4* srcv = (const f32x4*)(xv + (size_t)(m0 + m) * 768);
        #pragma unroll
        for (int it = 0; it < 3; ++it) {
            int ch = lane + it * 64;
            f32x4 v = __builtin_nontemporal_load(&srcv[ch]);
            int e0 = ch * 4;
            #pragma unroll
            for (int j = 0; j < 4; ++j) {
                int e = e0 + j;
                int c = e / 3;
                int i = e - c * 3;
                feat[m * 13 + 10 + i][c ^ mx] = f2bf(v[j]);
            }
        }
        {
            f32x4 v = __builtin_nontemporal_load(&((const f32x4*)(xa + (size_t)(m0 + m) * 256))[lane]);
            // 4 consecutive u16 stay contiguous & 8B-aligned under ^mx (mx bits >= 3)
            u16x4 w4;
            #pragma unroll
            for (int j = 0; j < 4; ++j) w4[j] = f2bf(v[j]);
            *(u16x4*)&feat[m * 13 + 9][(lane * 4) ^ mx] = w4;
        }
    }
    __syncthreads();    // the only barrier: feat is read-only from here on

    const int am  = lane & 7;    // token row m (A rows 8..15 hold the paired slot)
    const int aq  = lane >> 4;   // k-quarter
    const int col = lane & 15;   // output channel within tile

    #pragma unroll 1
    for (int t = 0; t < 2; ++t) {
        const int o = t * 128 + wid * 16 + col;

        // paired accs: {low-slot | high-slot} ; singles duplicate rows
        f32x4 cP0{}, cP1{}, cP2{}, cP3{};   // (t0|t1)(t2|t3)(t4|t5)(t6|t7)
        f32x4 cS8{}, cSd{};                 // t8 ; delta (xa x Wtd)      [dup rows]
        f32x4 cW01{}, cW2{};                // (w0|w1) ; w2 [dup rows]
        f32x4 cA04{}, cA8{};                // (Wa@d0|Wa@d4) ; Wa@d8 [dup rows]
        f32x4 cV57{}, cV62{}, cV13{};       // (Wv@d5|Wv@d7)(Wv@d6|Wv@d2)(Wv@d1|Wv@d3)

#define AP(qa, qb) (*(const bf16x8*)(fb + ((lane & 8) ? (qb) : (qa)) * FPAD))
#define AD(q)      (*(const bf16x8*)(fb + (q) * FPAD))

        #pragma unroll 2
        for (int ks = 0; ks < 8; ++ks) {
            const int csw = (ks * 32 + aq * 8) ^ (am << 3);
            const unsigned short* fb = &feat[am * 13][csw];
            bf16x8 a01 = AP(0, 1),  a23 = AP(2, 3), a45 = AP(4, 5), a67 = AP(6, 7);
            bf16x8 a8  = AD(8),     a9  = AD(9);
            bf16x8 aW  = AP(10, 11), aW2 = AD(12);
            bf16x8 a04 = AP(0, 4),  a57 = AP(5, 7), a62 = AP(6, 2), a13 = AP(1, 3);

            // dense fragment-ordered weight loads: 16 B/lane contiguous per matrix
            const unsigned short* wsb = ws + ((((t * 8 + wid) * 8 + ks) * 5) * 64 + lane) * 8;
            bf16x8 b_tt = *(const bf16x8*)(wsb + 0 * 512);
            bf16x8 b_td = *(const bf16x8*)(wsb + 1 * 512);
            bf16x8 b_vd = *(const bf16x8*)(wsb + 2 * 512);
            bf16x8 b_wa = *(const bf16x8*)(wsb + 3 * 512);
            bf16x8 b_wv = *(const bf16x8*)(wsb + 4 * 512);

            cP0  = __builtin_amdgcn_mfma_f32_16x16x32_bf16(a01, b_tt, cP0, 0, 0, 0);
            cP1  = __builtin_amdgcn_mfma_f32_16x16x32_bf16(a23, b_tt, cP1, 0, 0, 0);
            cP2  = __builtin_amdgcn_mfma_f32_16x16x32_bf16(a45, b_tt, cP2, 0, 0, 0);
            cP3  = __builtin_amdgcn_mfma_f32_16x16x32_bf16(a67, b_tt, cP3, 0, 0, 0);
            cS8  = __builtin_amdgcn_mfma_f32_16x16x32_bf16(a8,  b_tt, cS8, 0, 0, 0);
            cSd  = __builtin_amdgcn_mfma_f32_16x16x32_bf16(a9,  b_td, cSd, 0, 0, 0);
            cW01 = __builtin_amdgcn_mfma_f32_16x16x32_bf16(aW,  b_vd, cW01, 0, 0, 0);
            cW2  = __builtin_amdgcn_mfma_f32_16x16x32_bf16(aW2, b_vd, cW2, 0, 0, 0);
            cA04 = __builtin_amdgcn_mfma_f32_16x16x32_bf16(a04, b_wa, cA04, 0, 0, 0);
            cA8  = __builtin_amdgcn_mfma_f32_16x16x32_bf16(a8,  b_wa, cA8, 0, 0, 0);
            cV57 = __builtin_amdgcn_mfma_f32_16x16x32_bf16(a57, b_wv, cV57, 0, 0, 0);
            cV62 = __builtin_amdgcn_mfma_f32_16x16x32_bf16(a62, b_wv, cV62, 0, 0, 0);
            cV13 = __builtin_amdgcn_mfma_f32_16x16x32_bf16(a13, b_wv, cV13, 0, 0, 0);
        }

        // ---- identity K-step: fold xd/xa residuals into accs (t[q] += d[T(q)]) ----
        // B = one-hot: bi[n][k] = 1 iff k_global == o(n). Dup accs use AD (both halves).
        {
            const int ob   = t * 128 + wid * 16;
            const int cw32 = ob & ~31;           // 32-aligned c-window containing o-range
            const int hit  = (ob & 31) + col - aq * 8;
            bf16x8 bi;
            #pragma unroll
            for (int j = 0; j < 8; ++j) bi[j] = (short)((hit == j) ? 0x3F80 : 0);
            const int csw = (cw32 + aq * 8) ^ (am << 3);
            const unsigned short* fb = &feat[am * 13][csw];
            // T: 0->0 1->3 2->6 3->1 4->4 5->7 6->2 7->5 8->8
            cP0 = __builtin_amdgcn_mfma_f32_16x16x32_bf16(AP(0, 3), bi, cP0, 0, 0, 0);
            cP1 = __builtin_amdgcn_mfma_f32_16x16x32_bf16(AP(6, 1), bi, cP1, 0, 0, 0);
            cP2 = __builtin_amdgcn_mfma_f32_16x16x32_bf16(AP(4, 7), bi, cP2, 0, 0, 0);
            cP3 = __builtin_amdgcn_mfma_f32_16x16x32_bf16(AP(2, 5), bi, cP3, 0, 0, 0);
            cS8 = __builtin_amdgcn_mfma_f32_16x16x32_bf16(AD(8),    bi, cS8, 0, 0, 0);
            cA8 = __builtin_amdgcn_mfma_f32_16x16x32_bf16(AD(9),    bi, cA8, 0, 0, 0);
        }
#undef AP
#undef AD

        // half-exchange: e = low-slot value on every lane, oo = high-slot value.
#define SWAPEO(e, oo, src) { \
            _Pragma("unroll") \
            for (int j = 0; j < 4; ++j) { \
                float a_ = (src)[j], b_ = (src)[j]; \
                asm volatile("v_permlane32_swap_b32 %0, %1" : "+v"(a_), "+v"(b_)); \
                (e)[j] = a_; (oo)[j] = b_; } }
        f32x4 t0v, t1v, t2v, t3v, t4v, t5v, t6v, t7v;
        f32x4 w0v, w1v, xa0v, xa4v, a5v, a7v, a6v, a2v, a1v, a3v;
        SWAPEO(t0v, t1v, cP0);  SWAPEO(t2v, t3v, cP1);
        SWAPEO(t4v, t5v, cP2);  SWAPEO(t6v, t7v, cP3);
        SWAPEO(w0v, w1v, cW01); SWAPEO(xa0v, xa4v, cA04);
        SWAPEO(a5v, a7v, cV57); SWAPEO(a6v, a2v, cV62); SWAPEO(a1v, a3v, cV13);
#undef SWAPEO

        // epilogue: residual-free xd/xa (identity-folded); xv residual from LDS.
        // Direct cached scattered stores. lane<32 -> r=0,1 ; lane>=32 -> r=2,3
        {
            const int hi = (lane >> 4) & 1;
#define EPI(R)                                                                  \
            {                                                                   \
                const int m   = hi * 4 + (R);                                   \
                const int cso = o ^ (m << 3);                                   \
                const float delta = cSd[(R)];                                   \
                const float w0 = w0v[(R)], w1 = w1v[(R)], w2 = cW2[(R)];        \
                const size_t row = (size_t)(m0 + m) * 256 + o;                  \
                float* po = out_xd + row * 9;                                   \
                po[0] = t0v[(R)] + delta;                                       \
                po[1] = t3v[(R)] - w2;                                          \
                po[2] = t6v[(R)] + w1;                                          \
                po[3] = t1v[(R)] + w2;                                          \
                po[4] = t4v[(R)] + delta;                                       \
                po[5] = t7v[(R)] - w0;                                          \
                po[6] = t2v[(R)] - w1;                                          \
                po[7] = t5v[(R)] + w0;                                          \
                po[8] = cS8[(R)] + delta;                                       \
                out_xa[row] = xa0v[(R)] + xa4v[(R)] + cA8[(R)];                 \
                const size_t vrow = row * 3;                                    \
                out_xv[vrow + 0] = bf2f(feat[m * 13 + 10][cso]) + a5v[(R)] - a7v[(R)]; \
                out_xv[vrow + 1] = bf2f(feat[m * 13 + 11][cso]) + a6v[(R)] - a2v[(R)]; \
                out_xv[vrow + 2] = bf2f(feat[m * 13 + 12][cso]) + a1v[(R)] - a3v[(R)]; \
            }
            if (lane < 32) { EPI(0); EPI(1); }
            else           { EPI(2); EPI(3); }
#undef EPI
        }
        // no barrier: feat stays read-only, outputs disjoint per lane
    }
}

extern "C" void kernel_launch(void* const* d_in, const int* in_sizes, int n_in,
                              void* d_out, int out_size, void* d_ws, size_t ws_size,
                              hipStream_t stream) {
    const float* xa  = (const float*)d_in[0];
    const float* xv  = (const float*)d_in[1];
    const float* xd  = (const float*)d_in[2];
    const float* Wtt = (const float*)d_in[3];
    const float* Wtr = (const float*)d_in[4];
    const float* Wtd = (const float*)d_in[5];
    const float* Wvd = (const float*)d_in[6];
    const float* Wdv = (const float*)d_in[7];
    unsigned short* ws = (unsigned short*)d_ws;
    float* out = (float*)d_out;

    avd_prep_kernel<<<dim3(128), dim3(512), 0, stream>>>(Wtt, Wtr, Wtd, Wvd, Wdv, ws);
    avd_main_kernel<<<dim3(16384 / TM), dim3(512), 0, stream>>>(xa, xv, xd, ws, out);
}

// Round 16
// 142.826 us; speedup vs baseline: 1.2355x; 1.0051x over previous
//
#include <hip/hip_runtime.h>

typedef __attribute__((ext_vector_type(8))) short bf16x8;
typedef __attribute__((ext_vector_type(4))) unsigned short u16x4;
typedef __attribute__((ext_vector_type(4))) float f32x4;

#define TM 8           // tokens per block
#define FPAD 272       // feat row stride (u16): 544 B = 34*16B -> uniform-4 bank tiling

__device__ __forceinline__ unsigned short f2bf(float f) {
    unsigned u = __builtin_bit_cast(unsigned, f);
    u += 0x7FFFu + ((u >> 16) & 1u);        // RNE
    return (unsigned short)(u >> 16);
}
__device__ __forceinline__ float bf2f(unsigned short h) {
    return __builtin_bit_cast(float, (unsigned)h << 16);
}

// ws layout: fragment order, 5 matrices. u16 index = (((tile*8+ks)*5 + w)*64 + lane)*8 + j
// lane = aq*16 + col ; value = Wmat_w[o = tile*16+col][c = ks*32 + aq*8 + j]
// w: 0 WTT, 1 WTD, 2 WVD, 3 WA, 4 WV.  Total 327680 u16 = 655 KB.
__device__ __forceinline__ int widx(int w, int o, int c) {
    int tile = o >> 4, col = o & 15;
    int ks = c >> 5, aq = (c >> 3) & 3, j = c & 7;
    return (((tile * 8 + ks) * 5 + w) * 64 + aq * 16 + col) * 8 + j;
}

// ---------------- prep: Wa = Wtr(I+Wtt), Wv = Wdv(I-Wtt), bf16 + fragment order ----------------
__global__ __launch_bounds__(512)
void avd_prep_kernel(const float* __restrict__ Wtt, const float* __restrict__ Wtr,
                     const float* __restrict__ Wtd, const float* __restrict__ Wvd,
                     const float* __restrict__ Wdv, unsigned short* __restrict__ ws)
{
    __shared__ float ra[2][256], rv[2][256];
    const int half = threadIdx.x >> 8;          // 0..1
    const int c    = threadIdx.x & 255;
    const int o    = blockIdx.x * 2 + half;
    ra[half][c] = Wtr[o * 256 + c];
    rv[half][c] = Wdv[o * 256 + c];
    __syncthreads();
    float sa = 0.f, sv = 0.f;
    #pragma unroll 8
    for (int k = 0; k < 256; ++k) {
        float w = Wtt[k * 256 + c];             // coalesced across c
        sa += ra[half][k] * w;
        sv += rv[half][k] * w;
    }
    const int idx = o * 256 + c;
    ws[widx(0, o, c)] = f2bf(Wtt[idx]);
    ws[widx(1, o, c)] = f2bf(Wtd[idx]);
    ws[widx(2, o, c)] = f2bf(Wvd[idx]);
    ws[widx(3, o, c)] = f2bf(Wtr[idx] + sa);    // Wa = Wtr(I+Wtt)
    ws[widx(4, o, c)] = f2bf(Wdv[idx] - sv);    // Wv = Wdv(I-Wtt)
}

// ---------------- main: single-layer fused, slot-paired MFMAs, identity-residual ----------------
__global__ __launch_bounds__(512, 4)
void avd_main_kernel(const float* __restrict__ xa, const float* __restrict__ xv,
                     const float* __restrict__ xd,
                     const unsigned short* __restrict__ ws,
                     float* __restrict__ out)
{
    // feat row = m*13 + p ; p 0..8: x_d (q=i*3+j), 9: x_a, 10..12: x_v comps.
    __shared__ __attribute__((aligned(16))) unsigned short feat[104][FPAD];    // 55.25 KB

    const int tid  = threadIdx.x;
    const int lane = tid & 63;
    const int wid  = tid >> 6;          // 0..7
    const int m0   = blockIdx.x * TM;

    float* out_xa = out;                 // 16384*256
    float* out_xv = out + 4194304;       // + 16384*256*3
    float* out_xd = out + 16777216;      // + 16384*256*9

    // ---- stage: wave `wid` owns token m = wid; dense f32x4 NT loads, u16 LDS scatter ----
    {
        const int m  = wid;
        const int mx = m << 3;
        const f32x4* srcd = (const f32x4*)(xd + (size_t)(m0 + m) * 2304);
        #pragma unroll
        for (int it = 0; it < 9; ++it) {
            int ch = lane + it * 64;
            f32x4 v = __builtin_nontemporal_load(&srcd[ch]);
            int e0 = ch * 4;
            #pragma unroll
            for (int j = 0; j < 4; ++j) {
                int e = e0 + j;
                int c = e / 9;
                int q = e - c * 9;
                feat[m * 13 + q][c ^ mx] = f2bf(v[j]);
            }
        }
        const f32x4* srcv = (const f32x4*)(xv + (size_t)(m0 + m) * 768);
        #pragma unroll
        for (int it = 0; it < 3; ++it) {
            int ch = lane + it * 64;
            f32x4 v = __builtin_nontemporal_load(&srcv[ch]);
            int e0 = ch * 4;
            #pragma unroll
            for (int j = 0; j < 4; ++j) {
                int e = e0 + j;
                int c = e / 3;
                int i = e - c * 3;
                feat[m * 13 + 10 + i][c ^ mx] = f2bf(v[j]);
            }
        }
        {
            f32x4 v = __builtin_nontemporal_load(&((const f32x4*)(xa + (size_t)(m0 + m) * 256))[lane]);
            // 4 consecutive u16 stay contiguous & 8B-aligned under ^mx (mx bits >= 3)
            u16x4 w4;
            #pragma unroll
            for (int j = 0; j < 4; ++j) w4[j] = f2bf(v[j]);
            *(u16x4*)&feat[m * 13 + 9][(lane * 4) ^ mx] = w4;
        }
    }
    __syncthreads();    // the only barrier: feat is read-only from here on

    const int am  = lane & 7;    // token row m (A rows 8..15 hold the paired slot)
    const int aq  = lane >> 4;   // k-quarter
    const int col = lane & 15;   // output channel within tile

    #pragma unroll 1
    for (int t = 0; t < 2; ++t) {
        const int o = t * 128 + wid * 16 + col;

        // paired accs: {low-slot | high-slot} ; singles duplicate rows
        f32x4 cP0{}, cP1{}, cP2{}, cP3{};   // (t0|t1)(t2|t3)(t4|t5)(t6|t7)
        f32x4 cS8{}, cSd{};                 // t8 ; delta (xa x Wtd)      [dup rows]
        f32x4 cW01{}, cW2{};                // (w0|w1) ; w2 [dup rows]
        f32x4 cA04{}, cA8{};                // (Wa@d0|Wa@d4) ; Wa@d8 [dup rows]
        f32x4 cV57{}, cV62{}, cV13{};       // (Wv@d5|Wv@d7)(Wv@d6|Wv@d2)(Wv@d1|Wv@d3)

#define AP(qa, qb) (*(const bf16x8*)(fb + ((lane & 8) ? (qb) : (qa)) * FPAD))
#define AD(q)      (*(const bf16x8*)(fb + (q) * FPAD))

        // T5: favor compute-phase waves on the CU scheduler. Waves here are
        // independent (no barrier) -> attn-like regime where setprio paid (m191).
        __builtin_amdgcn_s_setprio(1);

        #pragma unroll 2
        for (int ks = 0; ks < 8; ++ks) {
            const int csw = (ks * 32 + aq * 8) ^ (am << 3);
            const unsigned short* fb = &feat[am * 13][csw];
            bf16x8 a01 = AP(0, 1),  a23 = AP(2, 3), a45 = AP(4, 5), a67 = AP(6, 7);
            bf16x8 a8  = AD(8),     a9  = AD(9);
            bf16x8 aW  = AP(10, 11), aW2 = AD(12);
            bf16x8 a04 = AP(0, 4),  a57 = AP(5, 7), a62 = AP(6, 2), a13 = AP(1, 3);

            // dense fragment-ordered weight loads: 16 B/lane contiguous per matrix
            const unsigned short* wsb = ws + ((((t * 8 + wid) * 8 + ks) * 5) * 64 + lane) * 8;
            bf16x8 b_tt = *(const bf16x8*)(wsb + 0 * 512);
            bf16x8 b_td = *(const bf16x8*)(wsb + 1 * 512);
            bf16x8 b_vd = *(const bf16x8*)(wsb + 2 * 512);
            bf16x8 b_wa = *(const bf16x8*)(wsb + 3 * 512);
            bf16x8 b_wv = *(const bf16x8*)(wsb + 4 * 512);

            cP0  = __builtin_amdgcn_mfma_f32_16x16x32_bf16(a01, b_tt, cP0, 0, 0, 0);
            cP1  = __builtin_amdgcn_mfma_f32_16x16x32_bf16(a23, b_tt, cP1, 0, 0, 0);
            cP2  = __builtin_amdgcn_mfma_f32_16x16x32_bf16(a45, b_tt, cP2, 0, 0, 0);
            cP3  = __builtin_amdgcn_mfma_f32_16x16x32_bf16(a67, b_tt, cP3, 0, 0, 0);
            cS8  = __builtin_amdgcn_mfma_f32_16x16x32_bf16(a8,  b_tt, cS8, 0, 0, 0);
            cSd  = __builtin_amdgcn_mfma_f32_16x16x32_bf16(a9,  b_td, cSd, 0, 0, 0);
            cW01 = __builtin_amdgcn_mfma_f32_16x16x32_bf16(aW,  b_vd, cW01, 0, 0, 0);
            cW2  = __builtin_amdgcn_mfma_f32_16x16x32_bf16(aW2, b_vd, cW2, 0, 0, 0);
            cA04 = __builtin_amdgcn_mfma_f32_16x16x32_bf16(a04, b_wa, cA04, 0, 0, 0);
            cA8  = __builtin_amdgcn_mfma_f32_16x16x32_bf16(a8,  b_wa, cA8, 0, 0, 0);
            cV57 = __builtin_amdgcn_mfma_f32_16x16x32_bf16(a57, b_wv, cV57, 0, 0, 0);
            cV62 = __builtin_amdgcn_mfma_f32_16x16x32_bf16(a62, b_wv, cV62, 0, 0, 0);
            cV13 = __builtin_amdgcn_mfma_f32_16x16x32_bf16(a13, b_wv, cV13, 0, 0, 0);
        }

        // ---- identity K-step: fold xd/xa residuals into accs (t[q] += d[T(q)]) ----
        // B = one-hot: bi[n][k] = 1 iff k_global == o(n). Dup accs use AD (both halves).
        {
            const int ob   = t * 128 + wid * 16;
            const int cw32 = ob & ~31;           // 32-aligned c-window containing o-range
            const int hit  = (ob & 31) + col - aq * 8;
            bf16x8 bi;
            #pragma unroll
            for (int j = 0; j < 8; ++j) bi[j] = (short)((hit == j) ? 0x3F80 : 0);
            const int csw = (cw32 + aq * 8) ^ (am << 3);
            const unsigned short* fb = &feat[am * 13][csw];
            // T: 0->0 1->3 2->6 3->1 4->4 5->7 6->2 7->5 8->8
            cP0 = __builtin_amdgcn_mfma_f32_16x16x32_bf16(AP(0, 3), bi, cP0, 0, 0, 0);
            cP1 = __builtin_amdgcn_mfma_f32_16x16x32_bf16(AP(6, 1), bi, cP1, 0, 0, 0);
            cP2 = __builtin_amdgcn_mfma_f32_16x16x32_bf16(AP(4, 7), bi, cP2, 0, 0, 0);
            cP3 = __builtin_amdgcn_mfma_f32_16x16x32_bf16(AP(2, 5), bi, cP3, 0, 0, 0);
            cS8 = __builtin_amdgcn_mfma_f32_16x16x32_bf16(AD(8),    bi, cS8, 0, 0, 0);
            cA8 = __builtin_amdgcn_mfma_f32_16x16x32_bf16(AD(9),    bi, cA8, 0, 0, 0);
        }
#undef AP
#undef AD

        __builtin_amdgcn_s_setprio(0);

        // half-exchange: e = low-slot value on every lane, oo = high-slot value.
#define SWAPEO(e, oo, src) { \
            _Pragma("unroll") \
            for (int j = 0; j < 4; ++j) { \
                float a_ = (src)[j], b_ = (src)[j]; \
                asm volatile("v_permlane32_swap_b32 %0, %1" : "+v"(a_), "+v"(b_)); \
                (e)[j] = a_; (oo)[j] = b_; } }
        f32x4 t0v, t1v, t2v, t3v, t4v, t5v, t6v, t7v;
        f32x4 w0v, w1v, xa0v, xa4v, a5v, a7v, a6v, a2v, a1v, a3v;
        SWAPEO(t0v, t1v, cP0);  SWAPEO(t2v, t3v, cP1);
        SWAPEO(t4v, t5v, cP2);  SWAPEO(t6v, t7v, cP3);
        SWAPEO(w0v, w1v, cW01); SWAPEO(xa0v, xa4v, cA04);
        SWAPEO(a5v, a7v, cV57); SWAPEO(a6v, a2v, cV62); SWAPEO(a1v, a3v, cV13);
#undef SWAPEO

        // epilogue: residual-free xd/xa (identity-folded); xv residual from LDS.
        // Direct cached scattered stores. lane<32 -> r=0,1 ; lane>=32 -> r=2,3
        {
            const int hi = (lane >> 4) & 1;
#define EPI(R)                                                                  \
            {                                                                   \
                const int m   = hi * 4 + (R);                                   \
                const int cso = o ^ (m << 3);                                   \
                const float delta = cSd[(R)];                                   \
                const float w0 = w0v[(R)], w1 = w1v[(R)], w2 = cW2[(R)];        \
                const size_t row = (size_t)(m0 + m) * 256 + o;                  \
                float* po = out_xd + row * 9;                                   \
                po[0] = t0v[(R)] + delta;                                       \
                po[1] = t3v[(R)] - w2;                                          \
                po[2] = t6v[(R)] + w1;                                          \
                po[3] = t1v[(R)] + w2;                                          \
                po[4] = t4v[(R)] + delta;                                       \
                po[5] = t7v[(R)] - w0;                                          \
                po[6] = t2v[(R)] - w1;                                          \
                po[7] = t5v[(R)] + w0;                                          \
                po[8] = cS8[(R)] + delta;                                       \
                out_xa[row] = xa0v[(R)] + xa4v[(R)] + cA8[(R)];                 \
                const size_t vrow = row * 3;                                    \
                out_xv[vrow + 0] = bf2f(feat[m * 13 + 10][cso]) + a5v[(R)] - a7v[(R)]; \
                out_xv[vrow + 1] = bf2f(feat[m * 13 + 11][cso]) + a6v[(R)] - a2v[(R)]; \
                out_xv[vrow + 2] = bf2f(feat[m * 13 + 12][cso]) + a1v[(R)] - a3v[(R)]; \
            }
            if (lane < 32) { EPI(0); EPI(1); }
            else           { EPI(2); EPI(3); }
#undef EPI
        }
        // no barrier: feat stays read-only, outputs disjoint per lane
    }
}

extern "C" void kernel_launch(void* const* d_in, const int* in_sizes, int n_in,
                              void* d_out, int out_size, void* d_ws, size_t ws_size,
                              hipStream_t stream) {
    const float* xa  = (const float*)d_in[0];
    const float* xv  = (const float*)d_in[1];
    const float* xd  = (const float*)d_in[2];
    const float* Wtt = (const float*)d_in[3];
    const float* Wtr = (const float*)d_in[4];
    const float* Wtd = (const float*)d_in[5];
    const float* Wvd = (const float*)d_in[6];
    const float* Wdv = (const float*)d_in[7];
    unsigned short* ws = (unsigned short*)d_ws;
    float* out = (float*)d_out;

    avd_prep_kernel<<<dim3(128), dim3(512), 0, stream>>>(Wtt, Wtr, Wtd, Wvd, Wdv, ws);
    avd_main_kernel<<<dim3(16384 / TM), dim3(512), 0, stream>>>(xa, xv, xd, ws, out);
}